// Round 9
// baseline (101.411 us; speedup 1.0000x reference)
//
#include <hip/hip_runtime.h>
#include <math.h>

#define B_N  4
#define CIN  64
#define COUT 64
#define H_N  128
#define W_N  128

typedef _Float16 half8 __attribute__((ext_vector_type(8)));
typedef float    f32x4 __attribute__((ext_vector_type(4)));

#define KTOT   1728              // 27 groups (t*3+h) * 64 c
#define NSTEP  54                // KTOT / 32
#define WA_BYTES ((size_t)NSTEP * 4 * 64 * 8 * 2)   // 221184 B

// ---- pack weights (3,Cout,Cin,3,3) fp32 -> f16 in MFMA A-fragment order ----
// A-fragment for K-step s, m-tile mt, lane l: 8 f16 = A[m=mt*16+(l&15)][k=s*32+(l>>4)*8+j]
// k -> (t,h,c): g=k>>6, c=k&63, t=g/3, h=g%3
__global__ void wprep(const float* __restrict__ w, _Float16* __restrict__ wa) {
    int idx = blockIdx.x * 256 + threadIdx.x;        // (s, mt, lane)
    if (idx >= NSTEP * 4 * 64) return;
    int lane = idx & 63;
    int mt   = (idx >> 6) & 3;
    int s    = idx >> 8;
    int m    = mt * 16 + (lane & 15);
    int kl0  = (lane >> 4) * 8;
    _Float16 v[8];
#pragma unroll
    for (int j = 0; j < 8; ++j) {
        int k = s * 32 + kl0 + j;
        int g = k >> 6;
        int c = k & 63;
        int t = g / 3;
        int h = g % 3;
        v[j] = (_Float16)w[(((size_t)(h * COUT) + m) * CIN + c) * 9 + t];
    }
    *(int4*)&wa[(size_t)idx * 8] = *(int4*)v;
}

// XOR chunk-swizzle LDS layout: line = 64 halfs (128 B) per (plane, x);
// logical 16-B chunk lc of line xi lives at halfs offset xi*64 + ((lc ^ (xi&7))*8).
#define XS_LINE  64
#define XS_PLANE (130 * XS_LINE)         // 8320 halfs per plane (halo+128+halo)

// R10: two-plane LDS ring + split-nt B processing -> 3 blocks/CU.
// Ring: row r lives in plane r&1; row r+1 is written to plane (r+1)&1 =
// (r-1)&1, whose readers (taps of row r-1) all finished before the barrier
// that ended phase r-1 -- same barrier count as R9, LDS 49.9 -> 33.8 KB.
// Split-nt: B-fragments read and consumed in two halves (nt 0-3, then 4-7),
// halving bb liveness 64 -> 32 VGPR; per-element (t,h,kk) accumulation order
// unchanged (acc[nt] independent) -> bitwise-identical output.
__global__ __launch_bounds__(256, 3)
void conv_mfma(const float* __restrict__ inp, const float* __restrict__ depth,
               const _Float16* __restrict__ wa, const float* __restrict__ bias,
               const int* __restrict__ fptr, float* __restrict__ out) {
    __shared__ _Float16 Xs[2 * XS_PLANE];            // 33280 B
    __shared__ unsigned hLds[128];                   // per-pixel h-selection packs

    int bid  = blockIdx.x;
    int y    = bid & (H_N - 1);
    int b    = bid >> 7;
    int tid  = threadIdx.x;
    int lane = tid & 63;
    int mq   = tid >> 6;                             // wave id = m-quarter
    int ln15 = lane & 15;
    int quad = lane >> 4;

    // staging thread roles (fixed for all rows): 128 px x 2 c-halves
    int xl    = tid & 127;                           // x position
    int chalf = tid >> 7;                            // c in [chalf*32, chalf*32+32)
    int xi    = xl + 1;
    int key   = xi & 7;

    const size_t HW = (size_t)H_N * W_N;

#define LOAD_ROW(dyi, buf) {                                                  \
        int yy_ = y + (dyi) - 1;                                              \
        if (yy_ >= 0 && yy_ < H_N) {                                          \
            const float* src_ = inp + (((size_t)b * CIN + chalf * 32) * H_N + yy_) * W_N + xl; \
            _Pragma("unroll")                                                 \
            for (int cc = 0; cc < 32; ++cc) buf[cc] = src_[(size_t)cc * HW];  \
        } else {                                                              \
            _Pragma("unroll")                                                 \
            for (int cc = 0; cc < 32; ++cc) buf[cc] = 0.f;                    \
        }                                                                     \
    }

#define WRITE_ROW(pl, buf) {                                                  \
        _Float16 hb_[32];                                                     \
        _Pragma("unroll")                                                     \
        for (int cc = 0; cc < 32; ++cc) hb_[cc] = (_Float16)buf[cc];          \
        _Float16* dst_ = &Xs[(pl) * XS_PLANE + xi * XS_LINE];                 \
        _Pragma("unroll")                                                     \
        for (int k = 0; k < 4; ++k)                                           \
            *(int4*)&dst_[((chalf * 4 + k) ^ key) * 8] = *(int4*)&hb_[k * 8]; \
    }

    // ---- prologue: stage row 0 -> plane 0; zero pads (both planes, once);
    //      A(0) preload; h-pack ----
    const half8* wa8 = (const half8*)wa;   // frag index: (t*24 + j*4 + mt)*64 + lane
    half8 Abuf[2][6];

    float rbuf[32];
    LOAD_ROW(0, rbuf);

    {
        const half8* bA = wa8 + (size_t)mq * 64 + lane;
#pragma unroll
        for (int j = 0; j < 6; ++j) Abuf[0][j] = bA[(size_t)j * 4 * 64];
    }

    // zero pad lines xi=0 (x=-1) and xi=129 (x=128) for BOTH planes, once.
    // (x-halo is zero for every row, so ring reuse never dirties it.)
    if (tid < 32) {
        int pl  = tid >> 4;
        int rem = tid & 15;
        int xz  = (rem >= 8) ? 129 : 0;
        int k8  = rem & 7;
        int4 z  = {0, 0, 0, 0};
        *(int4*)&Xs[pl * XS_PLANE + xz * XS_LINE + k8 * 8] = z;
    }

    // h-selection packs: one pixel per thread (waves 0-1), LDS broadcast
    // u = (dw - d0)*(f/d0) + 1.5; dd==0 -> inv=inf/nan -> h=-1 (matches exact path)
    if (tid < 128) {
        int x = tid;
        double fd  = (double)(*fptr);
        float  d0f = depth[((size_t)b * H_N + y) * W_N + x];
        double dd  = (double)d0f;
        double inv = fd / dd;
        bool   pos = (inv > 0.0);
        unsigned pk = 0;
        for (int t = 0; t < 9; ++t) {
            int dy = t / 3 - 1, dx = t % 3 - 1;
            int yy = y + dy, xx = x + dx;
            float dwf = (yy >= 0 && yy < H_N && xx >= 0 && xx < W_N)
                        ? depth[((size_t)b * H_N + yy) * W_N + xx] : 0.f;
            int h = -1;
            if (pos) {
                double u  = ((double)dwf - dd) * inv + 1.5;
                double uf = floor(u);
                if (uf >= 0.0 && uf <= 2.0) h = (int)uf;
            }
            pk |= (unsigned)(h + 1) << (2 * t);
        }
        hLds[tid] = pk;
    }

    WRITE_ROW(0, rbuf);
    __syncthreads();

    unsigned hpk[8];
#pragma unroll
    for (int nt = 0; nt < 8; ++nt) hpk[nt] = hLds[nt * 16 + ln15];

    // ---- main loop: 3 phases (one dy-row each), 3 taps per phase ----
    f32x4 acc[8];                                    // [nt]
#pragma unroll
    for (int nt = 0; nt < 8; ++nt) acc[nt] = (f32x4){0.f, 0.f, 0.f, 0.f};

    half8 z8 = {(_Float16)0.f, (_Float16)0.f, (_Float16)0.f, (_Float16)0.f,
                (_Float16)0.f, (_Float16)0.f, (_Float16)0.f, (_Float16)0.f};

#pragma unroll
    for (int r = 0; r < 3; ++r) {
        int pr = r & 1;                              // plane holding row r

        // issue next row's global loads (land during this phase's MFMAs)
        float nbuf[32];
        if (r < 2) LOAD_ROW(r + 1, nbuf);

#pragma unroll
        for (int dxl = 0; dxl < 3; ++dxl) {
            int t  = r * 3 + dxl;
            int dx = dxl - 1;

            // A(t+1) prefetch into the other register buffer
            if (t < 8) {
                const half8* bA = wa8 + ((size_t)(t + 1) * 24 + mq) * 64 + lane;
#pragma unroll
                for (int j = 0; j < 6; ++j) Abuf[(t + 1) & 1][j] = bA[(size_t)j * 4 * 64];
            }

            // split-nt: two halves of 4 n-tiles each; bb liveness = 8 half8
#pragma unroll
            for (int g = 0; g < 2; ++g) {
                half8 bb[8];
#pragma unroll
                for (int ntl = 0; ntl < 4; ++ntl) {
                    int nt = g * 4 + ntl;
                    int xs = nt * 16 + ln15 + dx + 1;    // in [0, 129]
                    int k2 = xs & 7;
                    int ba = pr * XS_PLANE + xs * XS_LINE;
                    bb[ntl * 2 + 0] = *(const half8*)&Xs[ba + ((quad    ) ^ k2) * 8];
                    bb[ntl * 2 + 1] = *(const half8*)&Xs[ba + ((quad + 4) ^ k2) * 8];
                }
                // accumulation order per output element identical to R5-R9: (h, kk) asc
#pragma unroll
                for (int h = 0; h < 3; ++h) {
#pragma unroll
                    for (int kk = 0; kk < 2; ++kk) {
                        int j = h * 2 + kk;
#pragma unroll
                        for (int ntl = 0; ntl < 4; ++ntl) {
                            int nt = g * 4 + ntl;
                            int hb = (hpk[nt] >> (2 * t)) & 3;
                            half8 c = (hb == h + 1) ? bb[ntl * 2 + kk] : z8;
                            acc[nt] = __builtin_amdgcn_mfma_f32_16x16x32_f16(Abuf[t & 1][j], c, acc[nt], 0, 0, 0);
                        }
                    }
                }
            }
        }

        if (r < 2) {
            WRITE_ROW((r + 1) & 1, nbuf);            // ring: overwrite plane (r-1)&1
            __syncthreads();                         // row r+1 visible before its taps
        }
    }
#undef LOAD_ROW
#undef WRITE_ROW

    // ---- epilogue: D[m=o: quad*4+r][n=pixel: lane&15] + bias ----
#pragma unroll
    for (int nt = 0; nt < 8; ++nt) {
        int x = nt * 16 + ln15;
#pragma unroll
        for (int rr = 0; rr < 4; ++rr) {
            int o = mq * 16 + quad * 4 + rr;
            out[(((size_t)b * COUT + o) * H_N + y) * W_N + x] = acc[nt][rr] + bias[o];
        }
    }
}

// ---- fallback scalar kernel (used only if ws too small) ----
__global__ __launch_bounds__(256)
void conv25d(const float* __restrict__ inp, const float* __restrict__ depth,
             const float* __restrict__ wsrc, const float* __restrict__ bias,
             const int* __restrict__ fptr, float* __restrict__ out) {
    int bid = blockIdx.x;
    int xt  = bid & 3;
    int y   = (bid >> 2) & (H_N - 1);
    int b   = bid >> 9;
    int o   = threadIdx.x & 63;
    int q   = threadIdx.x >> 6;
    int x0  = xt * 32 + q * 8;
    double fd = (double)(*fptr);
    float acc[8];
    float bv = bias[o];
#pragma unroll
    for (int i = 0; i < 8; ++i) acc[i] = bv;
    const float* dcen = depth + ((size_t)b * H_N + y) * W_N;
    float d0[8];
#pragma unroll
    for (int i = 0; i < 8; ++i) d0[i] = dcen[x0 + i];
    for (int t = 0; t < 9; ++t) {
        int dy = t / 3 - 1, dx = t % 3 - 1;
        int yy = y + dy;
        if (yy < 0 || yy >= H_N) continue;
        const float* drow = depth + ((size_t)b * H_N + yy) * W_N;
        int hsel[8];
#pragma unroll
        for (int i = 0; i < 8; ++i) {
            int xx = x0 + i + dx;
            int h = -1;
            if (xx >= 0 && xx < W_N) {
                double dd = (double)d0[i];
                double s0 = dd / fd;
                if (s0 > 0.0) {
                    double u = ((double)drow[xx] - dd) / s0 + 1.5;
                    double uf = floor(u);
                    if (uf >= 0.0 && uf <= 2.0) h = (int)uf;
                }
            }
            hsel[i] = h;
        }
        const float* irow = inp + ((size_t)b * CIN * H_N + yy) * W_N;
        for (int c = 0; c < CIN; ++c) {
            const float* wb = wsrc + ((size_t)o * CIN + c) * 9 + t;
            float w0 = wb[0], w1 = wb[(size_t)COUT * CIN * 9], w2 = wb[2 * (size_t)COUT * CIN * 9];
            const float* ir = irow + (size_t)c * H_N * W_N;
#pragma unroll
            for (int i = 0; i < 8; ++i) {
                int h = hsel[i];
                if (h >= 0) {
                    float wv = (h == 0) ? w0 : ((h == 1) ? w1 : w2);
                    acc[i] = fmaf(ir[x0 + i + dx], wv, acc[i]);
                }
            }
        }
    }
    float* orow = out + (((size_t)b * COUT + o) * H_N + y) * W_N;
#pragma unroll
    for (int i = 0; i < 8; ++i) orow[x0 + i] = acc[i];
}

extern "C" void kernel_launch(void* const* d_in, const int* in_sizes, int n_in,
                              void* d_out, int out_size, void* d_ws, size_t ws_size,
                              hipStream_t stream) {
    const float* inp   = (const float*)d_in[0];
    const float* depth = (const float*)d_in[1];
    const float* w     = (const float*)d_in[2];
    const float* bias  = (const float*)d_in[3];
    const int*   f     = (const int*)d_in[4];
    float* out = (float*)d_out;

    if (ws_size >= WA_BYTES) {
        _Float16* wa = (_Float16*)d_ws;
        wprep<<<NSTEP, 256, 0, stream>>>(w, wa);
        conv_mfma<<<B_N * H_N, 256, 0, stream>>>(inp, depth, wa, bias, f, out);
    } else {
        conv25d<<<B_N * H_N * (W_N / 32), 256, 0, stream>>>(inp, depth, w, bias, f, out);
    }
}

// Round 10
// 97.358 us; speedup vs baseline: 1.0416x; 1.0416x over previous
//
#include <hip/hip_runtime.h>
#include <math.h>

#define B_N  4
#define CIN  64
#define COUT 64
#define H_N  128
#define W_N  128

typedef _Float16 half8 __attribute__((ext_vector_type(8)));
typedef float    f32x4 __attribute__((ext_vector_type(4)));

#define KTOT   1728              // 27 groups (t*3+h) * 64 c
#define NSTEP  54                // KTOT / 32
#define WA_BYTES ((size_t)NSTEP * 4 * 64 * 8 * 2)   // 221184 B

// ---- pack weights (3,Cout,Cin,3,3) fp32 -> f16 in MFMA A-fragment order ----
// A-fragment for K-step s, m-tile mt, lane l: 8 f16 = A[m=mt*16+(l&15)][k=s*32+(l>>4)*8+j]
// k -> (t,h,c): g=k>>6, c=k&63, t=g/3, h=g%3
__global__ void wprep(const float* __restrict__ w, _Float16* __restrict__ wa) {
    int idx = blockIdx.x * 256 + threadIdx.x;        // (s, mt, lane)
    if (idx >= NSTEP * 4 * 64) return;
    int lane = idx & 63;
    int mt   = (idx >> 6) & 3;
    int s    = idx >> 8;
    int m    = mt * 16 + (lane & 15);
    int kl0  = (lane >> 4) * 8;
    _Float16 v[8];
#pragma unroll
    for (int j = 0; j < 8; ++j) {
        int k = s * 32 + kl0 + j;
        int g = k >> 6;
        int c = k & 63;
        int t = g / 3;
        int h = g % 3;
        v[j] = (_Float16)w[(((size_t)(h * COUT) + m) * CIN + c) * 9 + t];
    }
    *(int4*)&wa[(size_t)idx * 8] = *(int4*)v;
}

// XOR chunk-swizzle LDS layout: line = 64 halfs (128 B) per (plane, x);
// logical 16-B chunk lc of line xi lives at halfs offset xi*64 + ((lc ^ (xi&7))*8).
#define XS_LINE  64
#define XS_PLANE (130 * XS_LINE)         // 8320 halfs per plane (halo+128+halo)

// R11 = R10 minus the spill. R10's (256,3) cap (gfx950 unified VGPR/AGPR:
// ~168 total/wave at 3 waves/SIMD) forced scratch spills (FETCH 30.5 MB vs
// 17.5 ideal, VGPR_Count 84 arch + acc). Fix: SINGLE Abuf[6] with the A(t+1)
// prefetch placed AFTER the tap's last MFMA -- WAR only (MFMA operands latch
// at issue), so the loads still get a full tap of flight time, at -24 VGPR.
// Hot state ~144 < 168 -> 3 waves/SIMD with no spills.
// Ring + split-nt + accumulation order (t,h,kk) unchanged -> bitwise output.
__global__ __launch_bounds__(256, 3)
void conv_mfma(const float* __restrict__ inp, const float* __restrict__ depth,
               const _Float16* __restrict__ wa, const float* __restrict__ bias,
               const int* __restrict__ fptr, float* __restrict__ out) {
    __shared__ _Float16 Xs[2 * XS_PLANE];            // 33280 B
    __shared__ unsigned hLds[128];                   // per-pixel h-selection packs

    int bid  = blockIdx.x;
    int y    = bid & (H_N - 1);
    int b    = bid >> 7;
    int tid  = threadIdx.x;
    int lane = tid & 63;
    int mq   = tid >> 6;                             // wave id = m-quarter
    int ln15 = lane & 15;
    int quad = lane >> 4;

    // staging thread roles (fixed for all rows): 128 px x 2 c-halves
    int xl    = tid & 127;                           // x position
    int chalf = tid >> 7;                            // c in [chalf*32, chalf*32+32)
    int xi    = xl + 1;
    int key   = xi & 7;

    const size_t HW = (size_t)H_N * W_N;

#define LOAD_ROW(dyi, buf) {                                                  \
        int yy_ = y + (dyi) - 1;                                              \
        if (yy_ >= 0 && yy_ < H_N) {                                          \
            const float* src_ = inp + (((size_t)b * CIN + chalf * 32) * H_N + yy_) * W_N + xl; \
            _Pragma("unroll")                                                 \
            for (int cc = 0; cc < 32; ++cc) buf[cc] = src_[(size_t)cc * HW];  \
        } else {                                                              \
            _Pragma("unroll")                                                 \
            for (int cc = 0; cc < 32; ++cc) buf[cc] = 0.f;                    \
        }                                                                     \
    }

#define WRITE_ROW(pl, buf) {                                                  \
        _Float16 hb_[32];                                                     \
        _Pragma("unroll")                                                     \
        for (int cc = 0; cc < 32; ++cc) hb_[cc] = (_Float16)buf[cc];          \
        _Float16* dst_ = &Xs[(pl) * XS_PLANE + xi * XS_LINE];                 \
        _Pragma("unroll")                                                     \
        for (int k = 0; k < 4; ++k)                                           \
            *(int4*)&dst_[((chalf * 4 + k) ^ key) * 8] = *(int4*)&hb_[k * 8]; \
    }

    // ---- prologue: stage row 0 -> plane 0; zero pads (both planes, once);
    //      A(0) preload; h-pack ----
    const half8* wa8 = (const half8*)wa;   // frag index: (t*24 + j*4 + mt)*64 + lane
    half8 Abuf[6];

    float rbuf[32];
    LOAD_ROW(0, rbuf);

    {
        const half8* bA = wa8 + (size_t)mq * 64 + lane;
#pragma unroll
        for (int j = 0; j < 6; ++j) Abuf[j] = bA[(size_t)j * 4 * 64];
    }

    // zero pad lines xi=0 (x=-1) and xi=129 (x=128) for BOTH planes, once.
    // (x-halo is zero for every row, so ring reuse never dirties it.)
    if (tid < 32) {
        int pl  = tid >> 4;
        int rem = tid & 15;
        int xz  = (rem >= 8) ? 129 : 0;
        int k8  = rem & 7;
        int4 z  = {0, 0, 0, 0};
        *(int4*)&Xs[pl * XS_PLANE + xz * XS_LINE + k8 * 8] = z;
    }

    // h-selection packs: one pixel per thread (waves 0-1), LDS broadcast
    // u = (dw - d0)*(f/d0) + 1.5; dd==0 -> inv=inf/nan -> h=-1 (matches exact path)
    if (tid < 128) {
        int x = tid;
        double fd  = (double)(*fptr);
        float  d0f = depth[((size_t)b * H_N + y) * W_N + x];
        double dd  = (double)d0f;
        double inv = fd / dd;
        bool   pos = (inv > 0.0);
        unsigned pk = 0;
        for (int t = 0; t < 9; ++t) {
            int dy = t / 3 - 1, dx = t % 3 - 1;
            int yy = y + dy, xx = x + dx;
            float dwf = (yy >= 0 && yy < H_N && xx >= 0 && xx < W_N)
                        ? depth[((size_t)b * H_N + yy) * W_N + xx] : 0.f;
            int h = -1;
            if (pos) {
                double u  = ((double)dwf - dd) * inv + 1.5;
                double uf = floor(u);
                if (uf >= 0.0 && uf <= 2.0) h = (int)uf;
            }
            pk |= (unsigned)(h + 1) << (2 * t);
        }
        hLds[tid] = pk;
    }

    WRITE_ROW(0, rbuf);
    __syncthreads();

    unsigned hpk[8];
#pragma unroll
    for (int nt = 0; nt < 8; ++nt) hpk[nt] = hLds[nt * 16 + ln15];

    // ---- main loop: 3 phases (one dy-row each), 3 taps per phase ----
    f32x4 acc[8];                                    // [nt]
#pragma unroll
    for (int nt = 0; nt < 8; ++nt) acc[nt] = (f32x4){0.f, 0.f, 0.f, 0.f};

    half8 z8 = {(_Float16)0.f, (_Float16)0.f, (_Float16)0.f, (_Float16)0.f,
                (_Float16)0.f, (_Float16)0.f, (_Float16)0.f, (_Float16)0.f};

#pragma unroll
    for (int r = 0; r < 3; ++r) {
        int pr = r & 1;                              // plane holding row r

        // issue next row's global loads (land during this phase's MFMAs)
        float nbuf[32];
        if (r < 2) LOAD_ROW(r + 1, nbuf);

#pragma unroll
        for (int dxl = 0; dxl < 3; ++dxl) {
            int t  = r * 3 + dxl;
            int dx = dxl - 1;

            // split-nt: two halves of 4 n-tiles each; bb liveness = 8 half8
#pragma unroll
            for (int g = 0; g < 2; ++g) {
                half8 bb[8];
#pragma unroll
                for (int ntl = 0; ntl < 4; ++ntl) {
                    int nt = g * 4 + ntl;
                    int xs = nt * 16 + ln15 + dx + 1;    // in [0, 129]
                    int k2 = xs & 7;
                    int ba = pr * XS_PLANE + xs * XS_LINE;
                    bb[ntl * 2 + 0] = *(const half8*)&Xs[ba + ((quad    ) ^ k2) * 8];
                    bb[ntl * 2 + 1] = *(const half8*)&Xs[ba + ((quad + 4) ^ k2) * 8];
                }
                // accumulation order per output element identical to R5-R10: (h, kk) asc
#pragma unroll
                for (int h = 0; h < 3; ++h) {
#pragma unroll
                    for (int kk = 0; kk < 2; ++kk) {
                        int j = h * 2 + kk;
#pragma unroll
                        for (int ntl = 0; ntl < 4; ++ntl) {
                            int nt = g * 4 + ntl;
                            int hb = (hpk[nt] >> (2 * t)) & 3;
                            half8 c = (hb == h + 1) ? bb[ntl * 2 + kk] : z8;
                            acc[nt] = __builtin_amdgcn_mfma_f32_16x16x32_f16(Abuf[j], c, acc[nt], 0, 0, 0);
                        }
                    }
                }
            }

            // A(t+1) prefetch into the SAME buffer, after this tap's last
            // MFMA has issued: WAR only -> no wait, full tap of flight time.
            if (t < 8) {
                const half8* bA = wa8 + ((size_t)(t + 1) * 24 + mq) * 64 + lane;
#pragma unroll
                for (int j = 0; j < 6; ++j) Abuf[j] = bA[(size_t)j * 4 * 64];
            }
        }

        if (r < 2) {
            WRITE_ROW((r + 1) & 1, nbuf);            // ring: overwrite plane (r-1)&1
            __syncthreads();                         // row r+1 visible before its taps
        }
    }
#undef LOAD_ROW
#undef WRITE_ROW

    // ---- epilogue: D[m=o: quad*4+r][n=pixel: lane&15] + bias ----
#pragma unroll
    for (int nt = 0; nt < 8; ++nt) {
        int x = nt * 16 + ln15;
#pragma unroll
        for (int rr = 0; rr < 4; ++rr) {
            int o = mq * 16 + quad * 4 + rr;
            out[(((size_t)b * COUT + o) * H_N + y) * W_N + x] = acc[nt][rr] + bias[o];
        }
    }
}

// ---- fallback scalar kernel (used only if ws too small) ----
__global__ __launch_bounds__(256)
void conv25d(const float* __restrict__ inp, const float* __restrict__ depth,
             const float* __restrict__ wsrc, const float* __restrict__ bias,
             const int* __restrict__ fptr, float* __restrict__ out) {
    int bid = blockIdx.x;
    int xt  = bid & 3;
    int y   = (bid >> 2) & (H_N - 1);
    int b   = bid >> 9;
    int o   = threadIdx.x & 63;
    int q   = threadIdx.x >> 6;
    int x0  = xt * 32 + q * 8;
    double fd = (double)(*fptr);
    float acc[8];
    float bv = bias[o];
#pragma unroll
    for (int i = 0; i < 8; ++i) acc[i] = bv;
    const float* dcen = depth + ((size_t)b * H_N + y) * W_N;
    float d0[8];
#pragma unroll
    for (int i = 0; i < 8; ++i) d0[i] = dcen[x0 + i];
    for (int t = 0; t < 9; ++t) {
        int dy = t / 3 - 1, dx = t % 3 - 1;
        int yy = y + dy;
        if (yy < 0 || yy >= H_N) continue;
        const float* drow = depth + ((size_t)b * H_N + yy) * W_N;
        int hsel[8];
#pragma unroll
        for (int i = 0; i < 8; ++i) {
            int xx = x0 + i + dx;
            int h = -1;
            if (xx >= 0 && xx < W_N) {
                double dd = (double)d0[i];
                double s0 = dd / fd;
                if (s0 > 0.0) {
                    double u = ((double)drow[xx] - dd) / s0 + 1.5;
                    double uf = floor(u);
                    if (uf >= 0.0 && uf <= 2.0) h = (int)uf;
                }
            }
            hsel[i] = h;
        }
        const float* irow = inp + ((size_t)b * CIN * H_N + yy) * W_N;
        for (int c = 0; c < CIN; ++c) {
            const float* wb = wsrc + ((size_t)o * CIN + c) * 9 + t;
            float w0 = wb[0], w1 = wb[(size_t)COUT * CIN * 9], w2 = wb[2 * (size_t)COUT * CIN * 9];
            const float* ir = irow + (size_t)c * H_N * W_N;
#pragma unroll
            for (int i = 0; i < 8; ++i) {
                int h = hsel[i];
                if (h >= 0) {
                    float wv = (h == 0) ? w0 : ((h == 1) ? w1 : w2);
                    acc[i] = fmaf(ir[x0 + i + dx], wv, acc[i]);
                }
            }
        }
    }
    float* orow = out + (((size_t)b * COUT + o) * H_N + y) * W_N;
#pragma unroll
    for (int i = 0; i < 8; ++i) orow[x0 + i] = acc[i];
}

extern "C" void kernel_launch(void* const* d_in, const int* in_sizes, int n_in,
                              void* d_out, int out_size, void* d_ws, size_t ws_size,
                              hipStream_t stream) {
    const float* inp   = (const float*)d_in[0];
    const float* depth = (const float*)d_in[1];
    const float* w     = (const float*)d_in[2];
    const float* bias  = (const float*)d_in[3];
    const int*   f     = (const int*)d_in[4];
    float* out = (float*)d_out;

    if (ws_size >= WA_BYTES) {
        _Float16* wa = (_Float16*)d_ws;
        wprep<<<NSTEP, 256, 0, stream>>>(w, wa);
        conv_mfma<<<B_N * H_N, 256, 0, stream>>>(inp, depth, wa, bias, f, out);
    } else {
        conv25d<<<B_N * H_N * (W_N / 32), 256, 0, stream>>>(inp, depth, w, bias, f, out);
    }
}

// Round 11
// 96.609 us; speedup vs baseline: 1.0497x; 1.0078x over previous
//
#include <hip/hip_runtime.h>
#include <math.h>

#define B_N  4
#define CIN  64
#define COUT 64
#define H_N  128
#define W_N  128

typedef _Float16 half8 __attribute__((ext_vector_type(8)));
typedef float    f32x4 __attribute__((ext_vector_type(4)));

#define KTOT   1728              // 27 groups (t*3+h) * 64 c
#define NSTEP  54                // KTOT / 32
#define WA_BYTES ((size_t)NSTEP * 4 * 64 * 8 * 2)   // 221184 B

// ---- pack weights (3,Cout,Cin,3,3) fp32 -> f16 in MFMA A-fragment order ----
// A-fragment for K-step s, m-tile mt, lane l: 8 f16 = A[m=mt*16+(l&15)][k=s*32+(l>>4)*8+j]
// k -> (t,h,c): g=k>>6, c=k&63, t=g/3, h=g%3
__global__ void wprep(const float* __restrict__ w, _Float16* __restrict__ wa) {
    int idx = blockIdx.x * 256 + threadIdx.x;        // (s, mt, lane)
    if (idx >= NSTEP * 4 * 64) return;
    int lane = idx & 63;
    int mt   = (idx >> 6) & 3;
    int s    = idx >> 8;
    int m    = mt * 16 + (lane & 15);
    int kl0  = (lane >> 4) * 8;
    _Float16 v[8];
#pragma unroll
    for (int j = 0; j < 8; ++j) {
        int k = s * 32 + kl0 + j;
        int g = k >> 6;
        int c = k & 63;
        int t = g / 3;
        int h = g % 3;
        v[j] = (_Float16)w[(((size_t)(h * COUT) + m) * CIN + c) * 9 + t];
    }
    *(int4*)&wa[(size_t)idx * 8] = *(int4*)v;
}

// XOR chunk-swizzle LDS layout: line = 64 halfs (128 B) per (dy, x);
// logical 16-B chunk lc of line xi lives at halfs offset xi*64 + ((lc ^ (xi&7))*8).
#define XS_LINE 64
#define XS_ROW  (130 * XS_LINE)          // 8320 halfs per dy-plane (halo+128+halo)

// R12 = R9 reverted (best measured: 96.70 us). Block = full row (128 px x 64
// Cout), 512 blocks; wave = m-quarter (16 Cout) x 128 px (8 n-tiles).
// Row-pipelined staging; A single-prefetch double-buffer; (256,2) -> no spill.
// R11's 3-blocks/CU variant measured equal-or-worse -> occupancy is not the
// binding constraint; reverting to the best-measured configuration.
__global__ __launch_bounds__(256, 2)
void conv_mfma(const float* __restrict__ inp, const float* __restrict__ depth,
               const _Float16* __restrict__ wa, const float* __restrict__ bias,
               const int* __restrict__ fptr, float* __restrict__ out) {
    __shared__ _Float16 Xs[3 * XS_ROW];              // 49920 B
    __shared__ unsigned hLds[128];                   // per-pixel h-selection packs

    int bid  = blockIdx.x;
    int y    = bid & (H_N - 1);
    int b    = bid >> 7;
    int tid  = threadIdx.x;
    int lane = tid & 63;
    int mq   = tid >> 6;                             // wave id = m-quarter
    int ln15 = lane & 15;
    int quad = lane >> 4;

    // staging thread roles (fixed for all rows): 128 px x 2 c-halves
    int xl    = tid & 127;                           // x position
    int chalf = tid >> 7;                            // c in [chalf*32, chalf*32+32)
    int xi    = xl + 1;
    int key   = xi & 7;

    const size_t HW = (size_t)H_N * W_N;

#define LOAD_ROW(dyi, buf) {                                                  \
        int yy_ = y + (dyi) - 1;                                              \
        if (yy_ >= 0 && yy_ < H_N) {                                          \
            const float* src_ = inp + (((size_t)b * CIN + chalf * 32) * H_N + yy_) * W_N + xl; \
            _Pragma("unroll")                                                 \
            for (int cc = 0; cc < 32; ++cc) buf[cc] = src_[(size_t)cc * HW];  \
        } else {                                                              \
            _Pragma("unroll")                                                 \
            for (int cc = 0; cc < 32; ++cc) buf[cc] = 0.f;                    \
        }                                                                     \
    }

#define WRITE_ROW(dyi, buf) {                                                 \
        _Float16 hb_[32];                                                     \
        _Pragma("unroll")                                                     \
        for (int cc = 0; cc < 32; ++cc) hb_[cc] = (_Float16)buf[cc];          \
        _Float16* dst_ = &Xs[(dyi) * XS_ROW + xi * XS_LINE];                  \
        _Pragma("unroll")                                                     \
        for (int k = 0; k < 4; ++k)                                           \
            *(int4*)&dst_[((chalf * 4 + k) ^ key) * 8] = *(int4*)&hb_[k * 8]; \
    }

    // ---- prologue: stage row 0; zero pads (once); A(0) preload; h-pack ----
    const half8* wa8 = (const half8*)wa;   // frag index: (t*24 + j*4 + mt)*64 + lane
    half8 Abuf[2][6];

    float rbuf[32];
    LOAD_ROW(0, rbuf);

    {
        const half8* bA = wa8 + (size_t)mq * 64 + lane;
#pragma unroll
        for (int j = 0; j < 6; ++j) Abuf[0][j] = bA[(size_t)j * 4 * 64];
    }

    // zero pad lines xi=0 (x=-1) and xi=129 (x=128) for ALL 3 planes, once.
    if (tid < 48) {
        int dyi = tid / 16;
        int rem = tid % 16;
        int xz  = (rem >= 8) ? 129 : 0;
        int k8  = rem & 7;
        int4 z  = {0, 0, 0, 0};
        *(int4*)&Xs[dyi * XS_ROW + xz * XS_LINE + k8 * 8] = z;
    }

    // h-selection packs: one pixel per thread (waves 0-1), LDS broadcast
    // u = (dw - d0)*(f/d0) + 1.5; dd==0 -> inv=inf/nan -> h=-1 (matches exact path)
    if (tid < 128) {
        int x = tid;
        double fd  = (double)(*fptr);
        float  d0f = depth[((size_t)b * H_N + y) * W_N + x];
        double dd  = (double)d0f;
        double inv = fd / dd;
        bool   pos = (inv > 0.0);
        unsigned pk = 0;
        for (int t = 0; t < 9; ++t) {
            int dy = t / 3 - 1, dx = t % 3 - 1;
            int yy = y + dy, xx = x + dx;
            float dwf = (yy >= 0 && yy < H_N && xx >= 0 && xx < W_N)
                        ? depth[((size_t)b * H_N + yy) * W_N + xx] : 0.f;
            int h = -1;
            if (pos) {
                double u  = ((double)dwf - dd) * inv + 1.5;
                double uf = floor(u);
                if (uf >= 0.0 && uf <= 2.0) h = (int)uf;
            }
            pk |= (unsigned)(h + 1) << (2 * t);
        }
        hLds[tid] = pk;
    }

    WRITE_ROW(0, rbuf);
    __syncthreads();

    unsigned hpk[8];
#pragma unroll
    for (int nt = 0; nt < 8; ++nt) hpk[nt] = hLds[nt * 16 + ln15];

    // ---- main loop: 3 phases (one dy-row each), 3 taps per phase ----
    f32x4 acc[8];                                    // [nt]
#pragma unroll
    for (int nt = 0; nt < 8; ++nt) acc[nt] = (f32x4){0.f, 0.f, 0.f, 0.f};

    half8 z8 = {(_Float16)0.f, (_Float16)0.f, (_Float16)0.f, (_Float16)0.f,
                (_Float16)0.f, (_Float16)0.f, (_Float16)0.f, (_Float16)0.f};

#pragma unroll
    for (int r = 0; r < 3; ++r) {
        // issue next row's global loads (land during this phase's MFMAs)
        float nbuf[32];
        if (r < 2) LOAD_ROW(r + 1, nbuf);

#pragma unroll
        for (int dxl = 0; dxl < 3; ++dxl) {
            int t  = r * 3 + dxl;
            int dx = dxl - 1;

            // B(t): 16 ds_read_b128 from plane r
            half8 bb[16];
#pragma unroll
            for (int nt = 0; nt < 8; ++nt) {
                int xs = nt * 16 + ln15 + dx + 1;    // in [0, 129]
                int k2 = xs & 7;
                int ba = r * XS_ROW + xs * XS_LINE;
                bb[nt * 2 + 0] = *(const half8*)&Xs[ba + ((quad    ) ^ k2) * 8];
                bb[nt * 2 + 1] = *(const half8*)&Xs[ba + ((quad + 4) ^ k2) * 8];
            }

            // A(t+1) prefetch into the other register buffer
            if (t < 8) {
                const half8* bA = wa8 + ((size_t)(t + 1) * 24 + mq) * 64 + lane;
#pragma unroll
                for (int j = 0; j < 6; ++j) Abuf[(t + 1) & 1][j] = bA[(size_t)j * 4 * 64];
            }

            int hb[8];
#pragma unroll
            for (int nt = 0; nt < 8; ++nt) hb[nt] = (hpk[nt] >> (2 * t)) & 3;

            // accumulation order per output element identical to R5-R8: (h, kk) asc
#pragma unroll
            for (int h = 0; h < 3; ++h) {
#pragma unroll
                for (int kk = 0; kk < 2; ++kk) {
                    int j = h * 2 + kk;
#pragma unroll
                    for (int nt = 0; nt < 8; ++nt) {
                        half8 c = (hb[nt] == h + 1) ? bb[nt * 2 + kk] : z8;
                        acc[nt] = __builtin_amdgcn_mfma_f32_16x16x32_f16(Abuf[t & 1][j], c, acc[nt], 0, 0, 0);
                    }
                }
            }
        }

        if (r < 2) {
            WRITE_ROW(r + 1, nbuf);
            __syncthreads();                         // row r+1 visible before its taps
        }
    }
#undef LOAD_ROW
#undef WRITE_ROW

    // ---- epilogue: D[m=o: quad*4+r][n=pixel: lane&15] + bias ----
#pragma unroll
    for (int nt = 0; nt < 8; ++nt) {
        int x = nt * 16 + ln15;
#pragma unroll
        for (int rr = 0; rr < 4; ++rr) {
            int o = mq * 16 + quad * 4 + rr;
            out[(((size_t)b * COUT + o) * H_N + y) * W_N + x] = acc[nt][rr] + bias[o];
        }
    }
}

// ---- fallback scalar kernel (used only if ws too small) ----
__global__ __launch_bounds__(256)
void conv25d(const float* __restrict__ inp, const float* __restrict__ depth,
             const float* __restrict__ wsrc, const float* __restrict__ bias,
             const int* __restrict__ fptr, float* __restrict__ out) {
    int bid = blockIdx.x;
    int xt  = bid & 3;
    int y   = (bid >> 2) & (H_N - 1);
    int b   = bid >> 9;
    int o   = threadIdx.x & 63;
    int q   = threadIdx.x >> 6;
    int x0  = xt * 32 + q * 8;
    double fd = (double)(*fptr);
    float acc[8];
    float bv = bias[o];
#pragma unroll
    for (int i = 0; i < 8; ++i) acc[i] = bv;
    const float* dcen = depth + ((size_t)b * H_N + y) * W_N;
    float d0[8];
#pragma unroll
    for (int i = 0; i < 8; ++i) d0[i] = dcen[x0 + i];
    for (int t = 0; t < 9; ++t) {
        int dy = t / 3 - 1, dx = t % 3 - 1;
        int yy = y + dy;
        if (yy < 0 || yy >= H_N) continue;
        const float* drow = depth + ((size_t)b * H_N + yy) * W_N;
        int hsel[8];
#pragma unroll
        for (int i = 0; i < 8; ++i) {
            int xx = x0 + i + dx;
            int h = -1;
            if (xx >= 0 && xx < W_N) {
                double dd = (double)d0[i];
                double s0 = dd / fd;
                if (s0 > 0.0) {
                    double u = ((double)drow[xx] - dd) / s0 + 1.5;
                    double uf = floor(u);
                    if (uf >= 0.0 && uf <= 2.0) h = (int)uf;
                }
            }
            hsel[i] = h;
        }
        const float* irow = inp + ((size_t)b * CIN * H_N + yy) * W_N;
        for (int c = 0; c < CIN; ++c) {
            const float* wb = wsrc + ((size_t)o * CIN + c) * 9 + t;
            float w0 = wb[0], w1 = wb[(size_t)COUT * CIN * 9], w2 = wb[2 * (size_t)COUT * CIN * 9];
            const float* ir = irow + (size_t)c * H_N * W_N;
#pragma unroll
            for (int i = 0; i < 8; ++i) {
                int h = hsel[i];
                if (h >= 0) {
                    float wv = (h == 0) ? w0 : ((h == 1) ? w1 : w2);
                    acc[i] = fmaf(ir[x0 + i + dx], wv, acc[i]);
                }
            }
        }
    }
    float* orow = out + (((size_t)b * COUT + o) * H_N + y) * W_N;
#pragma unroll
    for (int i = 0; i < 8; ++i) orow[x0 + i] = acc[i];
}

extern "C" void kernel_launch(void* const* d_in, const int* in_sizes, int n_in,
                              void* d_out, int out_size, void* d_ws, size_t ws_size,
                              hipStream_t stream) {
    const float* inp   = (const float*)d_in[0];
    const float* depth = (const float*)d_in[1];
    const float* w     = (const float*)d_in[2];
    const float* bias  = (const float*)d_in[3];
    const int*   f     = (const int*)d_in[4];
    float* out = (float*)d_out;

    if (ws_size >= WA_BYTES) {
        _Float16* wa = (_Float16*)d_ws;
        wprep<<<NSTEP, 256, 0, stream>>>(w, wa);
        conv_mfma<<<B_N * H_N, 256, 0, stream>>>(inp, depth, wa, bias, f, out);
    } else {
        conv25d<<<B_N * H_N * (W_N / 32), 256, 0, stream>>>(inp, depth, w, bias, f, out);
    }
}